// Round 3
// baseline (175.027 us; speedup 1.0000x reference)
//
#include <hip/hip_runtime.h>

// PCILT conv2d: qdq(x,8b) conv qdq(W,8b), 3x3 s1 p1.
// 3-kernel pipeline, no intermediate xq8 buffer:
//   K1 absmax_part : per-block |x|,|W| partials (no atomics)
//   K2 quant_w_k   : 288 blocks fold the 72 W-partials -> sw, quantize W -> wt8
//   K3 conv_fused  : one block per (n, oh-pair). Folds partials -> sx,sw;
//                    quantizes its own 4 f32 window rows (L3-hot) via LDS
//                    short-tile transpose (verified K2 code) directly into the
//                    conv xs buffer; then 2 passes of 9-tap ds_read_b128 +
//                    mfma_i32_16x16x64_i8 (exact int math), dequant epilogue.
//                    Quant VALU + x reads hide under the 102.8 MB out-store floor.

typedef __attribute__((ext_vector_type(8))) short short8;
typedef __attribute__((ext_vector_type(4))) int   int4v;    // 16 packed i8 (A/B) or i32 C/D
typedef __attribute__((ext_vector_type(4))) float f32x4;
typedef __attribute__((ext_vector_type(4))) float float4v;
typedef __attribute__((ext_vector_type(8)))  signed char char8;
typedef __attribute__((ext_vector_type(16))) signed char char16;

#define N_IMG 16
#define C_IN 64
#define HW 112
#define O_CH 128
#define WPITCH 576        // bytes per o-row in wt8 (9 taps * 64 c)
#define XPITCH 80         // conv LDS bytes per ow-row (64 + 16 pad)
#define TP 72             // quant tile LDS pitch (halves)
#define NPART 3136        // absmax partial blocks (3136*256*4 float4 == nx4)

// ---------------- kernel 1: per-block absmax partials (NO atomics) ----------
__global__ __launch_bounds__(256) void absmax_part(const float* __restrict__ x,
                                                   const float* __restrict__ w,
                                                   float* __restrict__ part) {
    const int b = blockIdx.x, tid = threadIdx.x;
    const float4v* x4 = (const float4v*)x;
    const long base = (long)b * 1024 + tid;
    const float4v v0 = x4[base];
    const float4v v1 = x4[base + 256];
    const float4v v2 = x4[base + 512];
    const float4v v3 = x4[base + 768];
    float mx = fmaxf(fmaxf(fmaxf(fabsf(v0.x), fabsf(v0.y)), fmaxf(fabsf(v0.z), fabsf(v0.w))),
                     fmaxf(fmaxf(fabsf(v1.x), fabsf(v1.y)), fmaxf(fabsf(v1.z), fabsf(v1.w))));
    mx = fmaxf(mx, fmaxf(fmaxf(fabsf(v2.x), fabsf(v2.y)), fmaxf(fabsf(v2.z), fabsf(v2.w))));
    mx = fmaxf(mx, fmaxf(fmaxf(fabsf(v3.x), fabsf(v3.y)), fmaxf(fabsf(v3.z), fabsf(v3.w))));
    float mw = 0.f;
    if (b < 72) {   // 72*256 float4 == 73,728 W floats exactly
        const float4v q = ((const float4v*)w)[b * 256 + tid];
        mw = fmaxf(fmaxf(fabsf(q.x), fabsf(q.y)), fmaxf(fabsf(q.z), fabsf(q.w)));
    }
    #pragma unroll
    for (int off = 32; off > 0; off >>= 1) {
        mx = fmaxf(mx, __shfl_down(mx, off));
        mw = fmaxf(mw, __shfl_down(mw, off));
    }
    __shared__ float smx[4], smw[4];
    const int wave = tid >> 6, lane = tid & 63;
    if (lane == 0) { smx[wave] = mx; smw[wave] = mw; }
    __syncthreads();
    if (tid == 0) {
        part[b]         = fmaxf(fmaxf(smx[0], smx[1]), fmaxf(smx[2], smx[3]));
        part[NPART + b] = fmaxf(fmaxf(smw[0], smw[1]), fmaxf(smw[2], smw[3]));
    }
}

// -------- kernel 2: fold W partials -> sw; quantize W -> int8 wt8 ----------
__global__ __launch_bounds__(256) void quant_w_k(const float* __restrict__ w,
                                                 const float* __restrict__ part,
                                                 signed char* __restrict__ wt8) {
    const int tid = threadIdx.x;
    const int wave = tid >> 6, lane = tid & 63;
    float mw = (tid < 72) ? part[NPART + tid] : 0.f;
    #pragma unroll
    for (int off = 32; off > 0; off >>= 1)
        mw = fmaxf(mw, __shfl_down(mw, off));
    __shared__ float smw[4];
    if (lane == 0) smw[wave] = mw;
    __syncthreads();
    const float wm = fmaxf(fmaxf(smw[0], smw[1]), fmaxf(smw[2], smw[3]));
    const float sw = fmaxf(wm * (1.f / 127.f), 1e-8f);

    const int idx = blockIdx.x * 256 + tid;        // 288*256 == 73,728 == O*C*9 exactly
    const int kw = idx % 3;
    int t = idx / 3;
    const int kh = t % 3;
    t /= 3;
    const int c = t % C_IN;
    const int o = t / C_IN;
    float v = rintf(w[idx] / sw);
    v = fminf(fmaxf(v, -127.f), 127.f);
    wt8[o * WPITCH + (kh * 3 + kw) * C_IN + c] = (signed char)(int)v;
}

// ---------------- kernel 3: conv with inline x-quant ----------------
// One block per (n, oh-pair). Quantizes its 4 window rows from f32 x into xs
// (per-row LDS short-tile transpose), then 2 MFMA passes + dequant epilogue.
__global__ __launch_bounds__(256, 3) void conv_fused(const float* __restrict__ x,
                                                     const float* __restrict__ part,
                                                     const signed char* __restrict__ wt8,
                                                     float* __restrict__ out) {
    __shared__ __align__(16) signed char xs[4 * 114 * XPITCH];   // 36,480 B
    __shared__ __align__(16) short tile[HW * TP];                // 16,128 B
    __shared__ float smx[4], smw[4];
    const int tid = threadIdx.x;
    const int wave = tid >> 6, lane = tid & 63;
    const int quad = lane >> 4, l16 = lane & 15;
    const int g = tid & 3, wi = tid >> 2;
    // XCD swizzle: 896 = 8 * 112 exactly (bijective)
    const int lin = (blockIdx.x & 7) * 112 + (blockIdx.x >> 3);
    const int n = lin / 56, oh0 = (lin % 56) * 2;

    // ---- fold partials -> sx, sw (reads are L2/L3-hot; ~13 guarded loads) ----
    float mx = 0.f, mw = 0.f;
    #pragma unroll
    for (int i = 0; i < 13; ++i) {                  // 13*256 >= 3136
        const int idx = i * 256 + tid;
        if (idx < NPART) mx = fmaxf(mx, part[idx]);
    }
    if (tid < 72) mw = part[NPART + tid];
    #pragma unroll
    for (int off = 32; off > 0; off >>= 1) {
        mx = fmaxf(mx, __shfl_down(mx, off));
        mw = fmaxf(mw, __shfl_down(mw, off));
    }
    if (lane == 0) { smx[wave] = mx; smw[wave] = mw; }
    __syncthreads();
    const float xm = fmaxf(fmaxf(smx[0], smx[1]), fmaxf(smx[2], smx[3]));
    const float wm = fmaxf(fmaxf(smw[0], smw[1]), fmaxf(smw[2], smw[3]));
    const float sx = fmaxf(xm * (1.f / 127.f), 1e-8f);
    const float sw = fmaxf(wm * (1.f / 127.f), 1e-8f);
    const float s_deq = sx * sw;
    const float inv_sx = 1.f / sx;

    // ---- zero border columns (ow_lds = 0, 113): 4 rows x 2 cols x 4 chunks
    if (tid < 32) {
        const int r = tid >> 3, col = (tid >> 2) & 1, c16 = tid & 3;
        *(int4v*)(xs + (r * 114 + col * 113) * XPITCH + c16 * 16) = (int4v)0;
    }

    // ---- quantize 4 window rows (ih = oh0-1 .. oh0+2) into xs ----
    for (int wr = 0; wr < 4; ++wr) {
        const int ih = oh0 - 1 + wr;
        const bool valid = (unsigned)ih < (unsigned)HW;   // uniform per block
        #pragma unroll
        for (int i = 0; i < 7; ++i) {               // 7*256 = 1792 = 64c * 28 w-quads
            const int l = i * 256 + tid;
            const int c = l / 28, w4 = l - c * 28;
            float4v v = (float4v)0;
            if (valid)
                v = *(const float4v*)(x + ((long)(n * C_IN + c) * HW + ih) * HW + w4 * 4);
            float q[4];
            q[0] = fminf(fmaxf(rintf(v.x * inv_sx), -127.f), 127.f);
            q[1] = fminf(fmaxf(rintf(v.y * inv_sx), -127.f), 127.f);
            q[2] = fminf(fmaxf(rintf(v.z * inv_sx), -127.f), 127.f);
            q[3] = fminf(fmaxf(rintf(v.w * inv_sx), -127.f), 127.f);
            const int osw = ((c >> 3) ^ (w4 & 7)) * 8 + (c & 7);   // swizzled c position
            #pragma unroll
            for (int j = 0; j < 4; ++j)
                tile[(w4 * 4 + j) * TP + osw] = (short)q[j];
        }
        __syncthreads();
        // pack 16 int8 along c, write into xs row wr (interior cols 1..112)
        #pragma unroll
        for (int j = 0; j < 2; ++j) {
            const int ww = j * 64 + wi;
            if (ww < HW) {
                const int sw2 = (ww >> 2) & 7;
                const short8 s0 = *(const short8*)(tile + ww * TP + ((2 * g) ^ sw2) * 8);
                const short8 s1 = *(const short8*)(tile + ww * TP + ((2 * g + 1) ^ sw2) * 8);
                const char8 c0 = __builtin_convertvector(s0, char8);
                const char8 c1 = __builtin_convertvector(s1, char8);
                const char16 cc = __builtin_shufflevector(c0, c1,
                    0, 1, 2, 3, 4, 5, 6, 7, 8, 9, 10, 11, 12, 13, 14, 15);
                *(char16*)(xs + (wr * 114 + ww + 1) * XPITCH + g * 16) = cc;
            }
        }
        __syncthreads();    // tile reused next row; also orders xs writes
    }

    // B-fragment pointers: wave owns channels [wave*32, wave*32+32)
    const signed char* wrow0 = wt8 + (wave * 32 + l16) * WPITCH + quad * 16;
    const signed char* wrow1 = wrow0 + 16 * WPITCH;

    #pragma unroll
    for (int p = 0; p < 2; ++p) {
        int4v acc[7][2];
        #pragma unroll
        for (int mt = 0; mt < 7; ++mt) { acc[mt][0] = (int4v)0; acc[mt][1] = (int4v)0; }

        int4v bcur0 = *(const int4v*)(wrow0);       // L2-hot
        int4v bcur1 = *(const int4v*)(wrow1);
        int4v bnxt0, bnxt1;

        #pragma unroll
        for (int tap = 0; tap < 9; ++tap) {
            if (tap < 8) {                          // prefetch next tap's B frags
                bnxt0 = *(const int4v*)(wrow0 + (tap + 1) * C_IN);
                bnxt1 = *(const int4v*)(wrow1 + (tap + 1) * C_IN);
            }
            const signed char* rowb = xs + ((p + tap / 3) * 114 + (tap % 3) + l16) * XPITCH + quad * 16;
            #pragma unroll
            for (int mt = 0; mt < 7; ++mt) {
                const int4v afr = *(const int4v*)(rowb + mt * (16 * XPITCH));
                acc[mt][0] = __builtin_amdgcn_mfma_i32_16x16x64_i8(afr, bcur0, acc[mt][0], 0, 0, 0);
                acc[mt][1] = __builtin_amdgcn_mfma_i32_16x16x64_i8(afr, bcur1, acc[mt][1], 0, 0, 0);
            }
            bcur0 = bnxt0;
            bcur1 = bnxt1;
        }

        // ---- epilogue: dequant + store row oh0+p (4 consecutive ow per lane)
        const int oh = oh0 + p;
        #pragma unroll
        for (int mt = 0; mt < 7; ++mt) {
            #pragma unroll
            for (int ot = 0; ot < 2; ++ot) {
                const int o = wave * 32 + ot * 16 + l16;     // D col = lane&15
                const int mrow = mt * 16 + quad * 4;         // D row = quad*4 + reg
                const f32x4 v = __builtin_convertvector(acc[mt][ot], f32x4) * s_deq;
                *(f32x4*)(out + (((long)(n * O_CH + o) * HW + oh) * HW + mrow)) = v;
            }
        }
    }
}

extern "C" void kernel_launch(void* const* d_in, const int* in_sizes, int n_in,
                              void* d_out, int out_size, void* d_ws, size_t ws_size,
                              hipStream_t stream) {
    const float* x = (const float*)d_in[0];
    const float* W = (const float*)d_in[1];
    float* out = (float*)d_out;

    float* part = (float*)((char*)d_ws + 1024);                          // 25,088 B
    signed char* wt8 = (signed char*)((char*)d_ws + 32768);              // 73,728 B

    hipLaunchKernelGGL(absmax_part, dim3(NPART), dim3(256), 0, stream, x, W, part);
    hipLaunchKernelGGL(quant_w_k, dim3(288), dim3(256), 0, stream, W, part, wt8);
    hipLaunchKernelGGL(conv_fused, dim3(896), dim3(256), 0, stream, x, part, wt8, out);
}

// Round 4
// 168.269 us; speedup vs baseline: 1.0402x; 1.0402x over previous
//
#include <hip/hip_runtime.h>

// PCILT conv2d: qdq(x,8b) conv qdq(W,8b), 3x3 s1 p1.
// 3-kernel pipeline (round-1 verified structure + trims):
//   K1 absmax_part : 896 blocks, per-block |x| partials (14 float4/thread)
//                    + |W| partials (blocks 0..71). No atomics.
//   K2 quant_wx    : every block folds the 896+72 partials (L2-hot, 4 loads)
//                    -> sx,sw; quantizes W (blocks 0..287); quantizes its
//                    (n,h) x-row via LDS transpose -> xq8 NHWC int8.
//   K3 conv_kernel : one block per (n, 4-row band): stage 6 padded int8 rows
//                    to LDS ONCE, four 9-tap passes of ds_read_b128 +
//                    mfma_i32_16x16x64_i8 (exact int math), dequant epilogue.
//                    448 blocks = 8*56 XCD-bijective, 2 blocks/CU.

typedef __attribute__((ext_vector_type(8))) short short8;
typedef __attribute__((ext_vector_type(4))) int   int4v;    // 16 packed i8 (A/B) or i32 C/D
typedef __attribute__((ext_vector_type(4))) float f32x4;
typedef __attribute__((ext_vector_type(4))) float float4v;
typedef __attribute__((ext_vector_type(8)))  signed char char8;
typedef __attribute__((ext_vector_type(16))) signed char char16;

#define N_IMG 16
#define C_IN 64
#define HW 112
#define O_CH 128
#define WPITCH 576        // bytes per o-row in wt8 (9 taps * 64 c)
#define XPITCH 80         // conv LDS bytes per ow-row (64 + 16 pad)
#define TP 72             // quant tile LDS pitch (halves)
#define NPART 896         // absmax partial blocks (896*3584*4 floats == nx)

// ---------------- kernel 1: per-block absmax partials (NO atomics) ----------
__global__ __launch_bounds__(256) void absmax_part(const float* __restrict__ x,
                                                   const float* __restrict__ w,
                                                   float* __restrict__ part) {
    const int b = blockIdx.x, tid = threadIdx.x;
    const float4v* x4 = (const float4v*)x;
    const long base = (long)b * 3584 + tid;     // 896*3584 float4 == 12,845,056 floats
    float mx = 0.f, mw = 0.f;
    #pragma unroll
    for (int i = 0; i < 14; ++i) {
        const float4v v = x4[base + i * 256];
        mx = fmaxf(mx, fmaxf(fmaxf(fabsf(v.x), fabsf(v.y)), fmaxf(fabsf(v.z), fabsf(v.w))));
    }
    if (b < 72) {   // 72*256 float4 == 73,728 W floats exactly
        const float4v q = ((const float4v*)w)[b * 256 + tid];
        mw = fmaxf(fmaxf(fabsf(q.x), fabsf(q.y)), fmaxf(fabsf(q.z), fabsf(q.w)));
    }
    #pragma unroll
    for (int off = 32; off > 0; off >>= 1) {
        mx = fmaxf(mx, __shfl_down(mx, off));
        mw = fmaxf(mw, __shfl_down(mw, off));
    }
    __shared__ float smx[4], smw[4];
    const int wave = tid >> 6, lane = tid & 63;
    if (lane == 0) { smx[wave] = mx; smw[wave] = mw; }
    __syncthreads();
    if (tid == 0) {
        part[b]         = fmaxf(fmaxf(smx[0], smx[1]), fmaxf(smx[2], smx[3]));
        part[NPART + b] = fmaxf(fmaxf(smw[0], smw[1]), fmaxf(smw[2], smw[3]));
    }
}

// -------- kernel 2: fold partials + quantize W + quantize/transpose x --------
// One block per (n,h). Each block folds the 896+72 partials itself (L2-hot).
// x path: float4 reads along w, LDS transpose (XOR-swizzled c-octets),
// pack 16 int8 per lane, char16 writes along c.
__global__ __launch_bounds__(256) void quant_wx(const float* __restrict__ x,
                                                const float* __restrict__ w,
                                                const float* __restrict__ part,
                                                unsigned* __restrict__ scal,
                                                signed char* __restrict__ wt8,
                                                signed char* __restrict__ xq8) {
    __shared__ __align__(16) short tile[HW * TP];   // quantized ints as short, 16,128 B
    __shared__ float smx[4], smw[4];
    const int tid = threadIdx.x;
    const int wave = tid >> 6, lane = tid & 63;

    // ---- fold partials (redundant per block; reads are cache-hot) ----
    float mx = 0.f, mw = 0.f;
    #pragma unroll
    for (int i = 0; i < 4; ++i) {                   // 4*256 >= 896
        const int idx = i * 256 + tid;
        if (idx < NPART) mx = fmaxf(mx, part[idx]);
    }
    if (tid < 72) mw = part[NPART + tid];
    #pragma unroll
    for (int off = 32; off > 0; off >>= 1) {
        mx = fmaxf(mx, __shfl_down(mx, off));
        mw = fmaxf(mw, __shfl_down(mw, off));
    }
    if (lane == 0) { smx[wave] = mx; smw[wave] = mw; }
    __syncthreads();
    const float xm = fmaxf(fmaxf(smx[0], smx[1]), fmaxf(smx[2], smx[3]));
    const float wm = fmaxf(fmaxf(smw[0], smw[1]), fmaxf(smw[2], smw[3]));
    const float sx = fmaxf(xm * (1.f / 127.f), 1e-8f);
    const float sw = fmaxf(wm * (1.f / 127.f), 1e-8f);
    if (blockIdx.x == 0 && tid == 0) {              // publish for conv epilogue
        scal[0] = __float_as_uint(xm);
        scal[1] = __float_as_uint(wm);
    }

    // ---- W quant (blocks 0..287 cover 288*256 == 73,728 == O*C*9 exactly) ----
    if (blockIdx.x < 288) {
        const int idx = blockIdx.x * 256 + tid;
        const int kw = idx % 3;
        int t = idx / 3;
        const int kh = t % 3;
        t /= 3;
        const int c = t % C_IN;
        const int o = t / C_IN;
        float v = rintf(w[idx] / sw);
        v = fminf(fmaxf(v, -127.f), 127.f);
        wt8[o * WPITCH + (kh * 3 + kw) * C_IN + c] = (signed char)(int)v;
    }

    // ---- x quant + transpose for this (n,h) row ----
    const int n = blockIdx.x / HW, h = blockIdx.x % HW;
    const float inv_sx = 1.f / sx;
    #pragma unroll
    for (int i = 0; i < 7; ++i) {                   // 7*256 = 1792 = 64c * 28 w-quads
        const int l = i * 256 + tid;
        const int c = l / 28, w4 = l - c * 28;
        const float4v v = *(const float4v*)(x + ((long)(n * C_IN + c) * HW + h) * HW + w4 * 4);
        float q[4];
        q[0] = fminf(fmaxf(rintf(v.x * inv_sx), -127.f), 127.f);
        q[1] = fminf(fmaxf(rintf(v.y * inv_sx), -127.f), 127.f);
        q[2] = fminf(fmaxf(rintf(v.z * inv_sx), -127.f), 127.f);
        q[3] = fminf(fmaxf(rintf(v.w * inv_sx), -127.f), 127.f);
        const int osw = ((c >> 3) ^ (w4 & 7)) * 8 + (c & 7);   // swizzled c position
        #pragma unroll
        for (int j = 0; j < 4; ++j)
            tile[(w4 * 4 + j) * TP + osw] = (short)q[j];
    }
    __syncthreads();
    const int g = tid & 3, wi = tid >> 2;           // 4 c-16-groups x 64 w-slots
    signed char* dst = xq8 + (long)(n * HW + h) * HW * C_IN;
    #pragma unroll
    for (int j = 0; j < 2; ++j) {
        const int ww = j * 64 + wi;
        if (ww < HW) {
            const int sw2 = (ww >> 2) & 7;
            const short8 s0 = *(const short8*)(tile + ww * TP + ((2 * g) ^ sw2) * 8);
            const short8 s1 = *(const short8*)(tile + ww * TP + ((2 * g + 1) ^ sw2) * 8);
            const char8 c0 = __builtin_convertvector(s0, char8);
            const char8 c1 = __builtin_convertvector(s1, char8);
            const char16 cc = __builtin_shufflevector(c0, c1,
                0, 1, 2, 3, 4, 5, 6, 7, 8, 9, 10, 11, 12, 13, 14, 15);
            *(char16*)(dst + ww * C_IN + g * 16) = cc;
        }
    }
}

// ---------------- kernel 3: conv — 4 output rows per block ----------------
// Stage 6 input rows (oh0-1..oh0+4) once; four 9-tap MFMA passes share them.
// 448 blocks (8*56, XCD-bijective swizzle), 54,720 B LDS -> 2 blocks/CU,
// 8 waves/CU; all blocks co-resident in one dispatch round.
__global__ __launch_bounds__(256, 2) void conv_kernel(const signed char* __restrict__ xq8,
                                                      const signed char* __restrict__ wt8,
                                                      const unsigned* __restrict__ scal,
                                                      float* __restrict__ out) {
    __shared__ __align__(16) signed char xs[6 * 114 * XPITCH];   // 54,720 B
    const int tid = threadIdx.x;
    const int wave = tid >> 6, lane = tid & 63;
    const int quad = lane >> 4, l16 = lane & 15;
    // XCD swizzle: 448 = 8 * 56 exactly (bijective)
    const int lin = (blockIdx.x & 7) * 56 + (blockIdx.x >> 3);
    const int n = lin / 28, oh0 = (lin % 28) * 4;

    // ---- zero border columns (ow_lds = 0, 113): 6 rows x 2 cols x 4 chunks
    if (tid < 48) {
        const int r = tid >> 3, col = (tid >> 2) & 1, c16 = tid & 3;
        *(int4v*)(xs + (r * 114 + col * 113) * XPITCH + c16 * 16) = (int4v)0;
    }
    // ---- stage 6 rows (ih = oh0-1 .. oh0+4): 2688 chunks, 11*256 guarded ----
    #pragma unroll
    for (int it = 0; it < 11; ++it) {
        const int gph = it * 256 + tid;             // 6 rows * 112 ow * 4 c16 = 2688
        if (gph < 2688) {
            const int r = gph / 448, rem = gph - r * 448;
            const int ow = rem >> 2, c16 = rem & 3;
            const int ih = oh0 - 1 + r;
            int4v v = (int4v)0;
            if ((unsigned)ih < (unsigned)HW)
                v = *(const int4v*)(xq8 + ((long)(n * HW + ih) * HW + ow) * C_IN + c16 * 16);
            *(int4v*)(xs + (r * 114 + ow + 1) * XPITCH + c16 * 16) = v;
        }
    }

    // B-fragment pointers: wave owns channels [wave*32, wave*32+32)
    const signed char* wrow0 = wt8 + (wave * 32 + l16) * WPITCH + quad * 16;
    const signed char* wrow1 = wrow0 + 16 * WPITCH;
    const float s = fmaxf(__uint_as_float(scal[0]) * (1.f / 127.f), 1e-8f) *
                    fmaxf(__uint_as_float(scal[1]) * (1.f / 127.f), 1e-8f);

    __syncthreads();

    #pragma unroll
    for (int p = 0; p < 4; ++p) {
        int4v acc[7][2];
        #pragma unroll
        for (int mt = 0; mt < 7; ++mt) { acc[mt][0] = (int4v)0; acc[mt][1] = (int4v)0; }

        int4v bcur0 = *(const int4v*)(wrow0);       // L1-hot after pass 0
        int4v bcur1 = *(const int4v*)(wrow1);
        int4v bnxt0, bnxt1;

        #pragma unroll
        for (int tap = 0; tap < 9; ++tap) {
            if (tap < 8) {                          // prefetch next tap's B frags
                bnxt0 = *(const int4v*)(wrow0 + (tap + 1) * C_IN);
                bnxt1 = *(const int4v*)(wrow1 + (tap + 1) * C_IN);
            }
            const signed char* rowb = xs + ((p + tap / 3) * 114 + (tap % 3) + l16) * XPITCH + quad * 16;
            #pragma unroll
            for (int mt = 0; mt < 7; ++mt) {
                const int4v afr = *(const int4v*)(rowb + mt * (16 * XPITCH));
                acc[mt][0] = __builtin_amdgcn_mfma_i32_16x16x64_i8(afr, bcur0, acc[mt][0], 0, 0, 0);
                acc[mt][1] = __builtin_amdgcn_mfma_i32_16x16x64_i8(afr, bcur1, acc[mt][1], 0, 0, 0);
            }
            bcur0 = bnxt0;
            bcur1 = bnxt1;
        }

        // ---- epilogue: dequant + store row oh0+p (4 consecutive ow per lane)
        const int oh = oh0 + p;
        #pragma unroll
        for (int mt = 0; mt < 7; ++mt) {
            #pragma unroll
            for (int ot = 0; ot < 2; ++ot) {
                const int o = wave * 32 + ot * 16 + l16;     // D col = lane&15
                const int mrow = mt * 16 + quad * 4;         // D row = quad*4 + reg
                const f32x4 v = __builtin_convertvector(acc[mt][ot], f32x4) * s;
                *(f32x4*)(out + (((long)(n * O_CH + o) * HW + oh) * HW + mrow)) = v;
            }
        }
    }
}

extern "C" void kernel_launch(void* const* d_in, const int* in_sizes, int n_in,
                              void* d_out, int out_size, void* d_ws, size_t ws_size,
                              hipStream_t stream) {
    const float* x = (const float*)d_in[0];
    const float* W = (const float*)d_in[1];
    float* out = (float*)d_out;

    unsigned* scal = (unsigned*)d_ws;                                    // 8 B
    float* part = (float*)((char*)d_ws + 1024);                          // 7,168 B
    signed char* wt8 = (signed char*)((char*)d_ws + 16384);              // 73,728 B
    signed char* xq8 = (signed char*)((char*)d_ws + 98304);              // 12,845,056 B

    hipLaunchKernelGGL(absmax_part, dim3(NPART), dim3(256), 0, stream, x, W, part);
    hipLaunchKernelGGL(quant_wx, dim3(N_IMG * HW), dim3(256), 0, stream,
                       x, W, part, scal, wt8, xq8);
    hipLaunchKernelGGL(conv_kernel, dim3(448), dim3(256), 0, stream, xq8, wt8, scal, out);
}